// Round 4
// baseline (377.836 us; speedup 1.0000x reference)
//
#include <hip/hip_runtime.h>
#include <math.h>

#define B       32
#define S_FULL  512
#define S       511            // sliced length (drop token 0)
#define D       768
#define NROWS   (B * S)        // 16352

#define TM 128
#define TN 128
#define NCHUNK 4
#define NKT 24                 // D / 32
#define EPS_MARGIN 6e-5f       // split-f16 RTZ sim error ~7e-7; ~80x safety
#define SIM_SCALE  512.0f      // lifts f16 ops out of denormal range

typedef __attribute__((ext_vector_type(8))) _Float16 f16x8;  // 8 fp16 (4 VGPRs)
typedef __attribute__((ext_vector_type(4))) float f32x4;

// fp16 hi/lo split of 8 consecutive floats (pre-scaled by s), RTZ pack (1 op / 2 elems).
// Also accumulates sum of squares of the scaled values (row-norm fusion).
__device__ inline void cvt8(const float4& v0, const float4& v1, float s,
                            f16x8& hv, f16x8& lv, float& nacc) {
    float x[8] = {v0.x, v0.y, v0.z, v0.w, v1.x, v1.y, v1.z, v1.w};
    #pragma unroll
    for (int e = 0; e < 8; e += 2) {
        float xa = x[e] * s, xb = x[e + 1] * s;
        nacc = fmaf(xa, xa, nacc);
        nacc = fmaf(xb, xb, nacc);
        auto h = __builtin_amdgcn_cvt_pkrtz(xa, xb);                      // __fp16 x2
        auto l = __builtin_amdgcn_cvt_pkrtz(xa - (float)h.x, xb - (float)h.y);
        hv[e] = (_Float16)h.x; hv[e + 1] = (_Float16)h.y;
        lv[e] = (_Float16)l.x; lv[e + 1] = (_Float16)l.y;
    }
}

// ---------------- 1. prep: image loss only (norms fused into GEMM now) ------
__global__ __launch_bounds__(256) void prep_kernel(
    const float* __restrict__ image, const float* __restrict__ target,
    float* __restrict__ acc)
{
    int row  = blockIdx.x * 4 + (threadIdx.x >> 6);   // 0..B*S_FULL-1
    int lane = threadIdx.x & 63;
    const float4* pi4 = (const float4*)(image  + (size_t)row * D);
    const float4* pg4 = (const float4*)(target + (size_t)row * D);
    float si = 0.f;
    #pragma unroll
    for (int q = 0; q < 3; ++q) {
        float4 m = pi4[lane + 64 * q];
        float4 g = pg4[lane + 64 * q];
        float dx = m.x-g.x, dy = m.y-g.y, dz = m.z-g.z, dw = m.w-g.w;
        si += dx*dx + dy*dy + dz*dz + dw*dw;
    }
    #pragma unroll
    for (int m = 32; m > 0; m >>= 1) si += __shfl_xor(si, m);
    if (lane == 0) atomicAdd(&acc[blockIdx.x & 63], si);
}

// ---------------- 2. split-fp16 MFMA GEMM + fused norms + per-chunk top-2 ---
// grid (4, NCHUNK, B); block 256 (4 waves); tile 128x128; SINGLE-buffer LDS,
// two barriers per k-step (R1-proven schedule). Raw rows staged (x512);
// normalization applied in the epilogue: x inv_g[col] before top-2 (order),
// x inv_t[row] before store (value).
// LDS row = 128 B = 8 slots of 16 B: [4 hi][4 lo], slot ^= (row&7) both sides.
__global__ __launch_bounds__(256, 2) void simargmax_kernel(
    const float* __restrict__ text, const float* __restrict__ target,
    float* __restrict__ inv_g,
    float* __restrict__ pv, float* __restrict__ ps, int* __restrict__ pj)
{
    __shared__ __align__(16) _Float16 As[TM * 64];   // 16 KB
    __shared__ __align__(16) _Float16 Bs[TM * 64];   // 16 KB
    __shared__ float itL[TM], igL[TM];

    const int i0 = blockIdx.x * TM;
    const int jc = blockIdx.y;
    const int j0 = jc * TN;
    const int b  = blockIdx.z;
    const int t  = threadIdx.x;
    const int lane = t & 63;
    const int wy = t >> 6;                    // wave row-strip 0..3
    const int quad = lane >> 4, cid = lane & 15;

    const float* Abase = text   + (size_t)b * S_FULL * D + D;   // skip token 0
    const float* Bbase = target + (size_t)b * S_FULL * D + D;

    // staging map: thread covers 32 contiguous B (8 floats) of one row;
    // 4 threads = 128 B contiguous per row; 2 row-passes (h) cover 128 rows.
    const int r0 = t >> 2;          // 0..63
    const int c0 = t & 3;           // 16-B slot index within hi region
    const int kq = c0 * 8;          // float col offset within the 32-wide k-tile

    const int sw8 = (r0 & 7) * 8;   // store-side swizzle (halfwords)
    const int fw8 = (cid & 7) * 8;  // frag-read swizzle (row&7 == cid&7)
    const int qh  = quad * 8;

    float na[2] = {0.f, 0.f}, nb[2] = {0.f, 0.f};   // row sumsq partials

    f32x4 acc[2][8];
    #pragma unroll
    for (int mt = 0; mt < 2; ++mt)
        #pragma unroll
        for (int nt = 0; nt < 8; ++nt)
            acc[mt][nt] = (f32x4){0.f, 0.f, 0.f, 0.f};

    for (int kt = 0; kt < NKT; ++kt) {
        const int k0 = kt * 32;
        float4 va[2][2], vb[2][2];
        #pragma unroll
        for (int h = 0; h < 2; ++h) {
            int gi = i0 + r0 + 64 * h;
            if (gi < S) {
                const float4* pa = (const float4*)(Abase + (size_t)gi * D + k0 + kq);
                va[h][0] = pa[0]; va[h][1] = pa[1];
            } else {
                va[h][0] = make_float4(0.f,0.f,0.f,0.f);
                va[h][1] = make_float4(0.f,0.f,0.f,0.f);
            }
            int gj = j0 + r0 + 64 * h;
            if (gj < S) {
                const float4* pb = (const float4*)(Bbase + (size_t)gj * D + k0 + kq);
                vb[h][0] = pb[0]; vb[h][1] = pb[1];
            } else {
                vb[h][0] = make_float4(0.f,0.f,0.f,0.f);
                vb[h][1] = make_float4(0.f,0.f,0.f,0.f);
            }
        }
        __syncthreads();   // prior tile's ds_reads drained before overwrite
        #pragma unroll
        for (int h = 0; h < 2; ++h) {
            int base = (r0 + 64 * h) * 64;
            f16x8 hv, lv;
            cvt8(va[h][0], va[h][1], SIM_SCALE, hv, lv, na[h]);
            *(f16x8*)&As[base + ((c0 * 8)      ^ sw8)] = hv;
            *(f16x8*)&As[base + ((32 + c0 * 8) ^ sw8)] = lv;
            cvt8(vb[h][0], vb[h][1], SIM_SCALE, hv, lv, nb[h]);
            *(f16x8*)&Bs[base + ((c0 * 8)      ^ sw8)] = hv;
            *(f16x8*)&Bs[base + ((32 + c0 * 8) ^ sw8)] = lv;
        }
        __syncthreads();

        f16x8 ah[2], al[2];
        #pragma unroll
        for (int mt = 0; mt < 2; ++mt) {
            int ad = (wy * 32 + mt * 16 + cid) * 64;
            ah[mt] = *(const f16x8*)&As[ad + ( qh       ^ fw8)];
            al[mt] = *(const f16x8*)&As[ad + ((32 + qh) ^ fw8)];
        }
        #pragma unroll
        for (int nt = 0; nt < 8; ++nt) {
            int bd = (nt * 16 + cid) * 64;
            f16x8 bh = *(const f16x8*)&Bs[bd + ( qh       ^ fw8)];
            f16x8 bl = *(const f16x8*)&Bs[bd + ((32 + qh) ^ fw8)];
            #pragma unroll
            for (int mt = 0; mt < 2; ++mt) {
                acc[mt][nt] = __builtin_amdgcn_mfma_f32_16x16x32_f16(ah[mt], bh, acc[mt][nt], 0, 0, 0);
                acc[mt][nt] = __builtin_amdgcn_mfma_f32_16x16x32_f16(ah[mt], bl, acc[mt][nt], 0, 0, 0);
                acc[mt][nt] = __builtin_amdgcn_mfma_f32_16x16x32_f16(al[mt], bh, acc[mt][nt], 0, 0, 0);
            }
        }
    }

    // ---- row-norm reduce (reuse As as float scratch; barrier first: last
    // k-step's ds_reads must drain before overwrite) ----
    __syncthreads();
    float* fsA = (float*)&As[0];                // 128*4 floats
    float* fsB = fsA + 4 * TM;                  // 128*4 floats
    #pragma unroll
    for (int h = 0; h < 2; ++h) {
        fsA[(r0 + 64 * h) * 4 + c0] = na[h];
        fsB[(r0 + 64 * h) * 4 + c0] = nb[h];
    }
    __syncthreads();
    if (t < TM) {
        float s = fsA[t*4] + fsA[t*4+1] + fsA[t*4+2] + fsA[t*4+3];
        itL[t] = (s > 0.f) ? (1.f / sqrtf(s)) : 0.f;   // = 1/(512*||t_row||)
    } else {
        int r = t - TM;
        float s = fsB[r*4] + fsB[r*4+1] + fsB[r*4+2] + fsB[r*4+3];
        float ig = (s > 0.f) ? (1.f / sqrtf(s)) : 0.f; // = 1/(512*||g_row||)
        igL[r] = ig;
        if (i0 == 0) {                          // single writer per (b,jc) slot
            int gj = j0 + r;
            if (gj < S) inv_g[b * S + gj] = ig; // scale-invariant for recheck argmax
        }
    }
    __syncthreads();

    // epilogue: per-row top-2 over this chunk's 128 cols, true-sim units.
    // C/D layout: col = cid (within n-tile), row = quad*4 + reg (within m-tile)
    float igr[8];
    #pragma unroll
    for (int nt = 0; nt < 8; ++nt) igr[nt] = igL[nt * 16 + cid];
    #pragma unroll
    for (int mt = 0; mt < 2; ++mt) {
        #pragma unroll
        for (int r = 0; r < 4; ++r) {
            float v1 = -INFINITY, v2 = -INFINITY; int j1 = -1;
            #pragma unroll
            for (int nt = 0; nt < 8; ++nt) {
                int col = j0 + nt * 16 + cid;
                float v = acc[mt][nt][r] * igr[nt];
                if (col < S) {
                    if (v > v1) { v2 = v1; v1 = v; j1 = col; }
                    else if (v > v2) v2 = v;
                }
            }
            #pragma unroll
            for (int m = 1; m < 16; m <<= 1) {
                float ov1 = __shfl_xor(v1, m);
                int   oj1 = __shfl_xor(j1, m);
                float ov2 = __shfl_xor(v2, m);
                if (ov1 > v1) { v2 = fmaxf(v1, ov2); v1 = ov1; j1 = oj1; }
                else          { v2 = fmaxf(v2, ov1); }
            }
            if (cid == 0) {
                int lrow = wy * 32 + mt * 16 + quad * 4 + r;
                int gi = i0 + lrow;
                if (gi < S) {
                    float it = itL[lrow];
                    size_t o = ((size_t)(b * S + gi) << 2) + jc;
                    pv[o] = v1 * it; ps[o] = v2 * it; pj[o] = j1;
                }
            }
        }
    }
}

// ---------------- 3. combine chunks; commit or flag; text loss ----------------
__global__ __launch_bounds__(256) void text_kernel(
    const float* __restrict__ text, const float* __restrict__ target,
    const int* __restrict__ pm,
    const float* __restrict__ pv, const float* __restrict__ ps, const int* __restrict__ pj,
    float* __restrict__ idx_f, float* __restrict__ acc,
    int* __restrict__ list, int* __restrict__ cnt)
{
    int row = blockIdx.x * 4 + (threadIdx.x >> 6);
    if (row >= NROWS) return;
    int lane = threadIdx.x & 63;
    int b = row / S, i = row - b * S;

    float v1 = -INFINITY, v2 = -INFINITY; int j1 = 0;
    #pragma unroll
    for (int c = 0; c < NCHUNK; ++c) {
        size_t o = ((size_t)row << 2) + c;
        float a1 = pv[o], a2 = ps[o]; int aj = pj[o];
        if (a1 > v1) { v2 = fmaxf(v1, a2); v1 = a1; j1 = aj; }
        else         { v2 = fmaxf(v2, a1); }
    }
    if (v1 - v2 < EPS_MARGIN) {          // too close for split-fp16: exact recheck
        if (lane == 0) { int p = atomicAdd(cnt, 1); list[p] = row; }
        return;
    }
    if (lane == 0) idx_f[row] = (float)j1;

    if (pm[b * S_FULL + i + 1] != 0) return;
    const float4* pt = (const float4*)(text   + (size_t)(b * S_FULL + i  + 1) * D);
    const float4* pg = (const float4*)(target + (size_t)(b * S_FULL + j1 + 1) * D);
    float s = 0.f;
    #pragma unroll
    for (int q = 0; q < 3; ++q) {
        float4 a = pt[lane + 64 * q];
        float4 g = pg[lane + 64 * q];
        float dx = a.x-g.x, dy = a.y-g.y, dz = a.z-g.z, dw = a.w-g.w;
        s += dx*dx + dy*dy + dz*dz + dw*dw;
    }
    #pragma unroll
    for (int m = 32; m > 0; m >>= 1) s += __shfl_xor(s, m);
    if (lane == 0) {
        atomicAdd(&acc[64  + (blockIdx.x & 63)], s);
        atomicAdd(&acc[128 + (blockIdx.x & 63)], 1.0f);
    }
}

// ---------------- 4. exact fp32 argmax re-check (throughput-shaped) ----------
__global__ __launch_bounds__(256) void recheck_kernel(
    const float* __restrict__ text, const float* __restrict__ target,
    const int* __restrict__ pm, const float* __restrict__ inv_g,
    const int* __restrict__ list, const int* __restrict__ cnt,
    float* __restrict__ idx_f, float* __restrict__ acc)
{
    __shared__ float wv[4];
    __shared__ int   wj[4];
    __shared__ int   bjf;
    const int t = threadIdx.x, w = t >> 6, lane = t & 63;
    const int n = *cnt;
    for (int it = blockIdx.x; it < n; it += gridDim.x) {
        int row = list[it];
        int b = row / S, i = row - b * S;
        const float4* tp = (const float4*)(text + (size_t)(b * S_FULL + i + 1) * D);
        float4 tr0 = tp[lane], tr1 = tp[lane + 64], tr2 = tp[lane + 128];
        const float* Gb = target + (size_t)b * S_FULL * D + D;
        const float* ig = inv_g + b * S;

        float bv = -INFINITY; int bj = 0;
        for (int j = w; j < S; j += 8) {       // wave w: j ≡ w (mod 4), 2 per iter
            const float4* g0 = (const float4*)(Gb + (size_t)j * D);
            int j2 = j + 4; bool ok2 = (j2 < S);
            const float4* g1 = (const float4*)(Gb + (size_t)(ok2 ? j2 : j) * D);
            float4 a0 = g0[lane], a1 = g0[lane + 64], a2 = g0[lane + 128];
            float4 c0 = g1[lane], c1 = g1[lane + 64], c2 = g1[lane + 128];
            float s0 = tr0.x*a0.x + tr0.y*a0.y + tr0.z*a0.z + tr0.w*a0.w
                     + tr1.x*a1.x + tr1.y*a1.y + tr1.z*a1.z + tr1.w*a1.w
                     + tr2.x*a2.x + tr2.y*a2.y + tr2.z*a2.z + tr2.w*a2.w;
            float s1 = tr0.x*c0.x + tr0.y*c0.y + tr0.z*c0.z + tr0.w*c0.w
                     + tr1.x*c1.x + tr1.y*c1.y + tr1.z*c1.z + tr1.w*c1.w
                     + tr2.x*c2.x + tr2.y*c2.y + tr2.z*c2.z + tr2.w*c2.w;
            #pragma unroll
            for (int m = 32; m > 0; m >>= 1) {
                s0 += __shfl_xor(s0, m);
                s1 += __shfl_xor(s1, m);
            }
            s0 *= ig[j];
            if (s0 > bv) { bv = s0; bj = j; }       // ascending j: first-max kept
            if (ok2) {
                s1 *= ig[j2];
                if (s1 > bv) { bv = s1; bj = j2; }
            }
        }
        if (lane == 0) { wv[w] = bv; wj[w] = bj; }
        __syncthreads();
        if (t == 0) {
            float fv = wv[0]; int fj = wj[0];
            #pragma unroll
            for (int q = 1; q < 4; ++q)
                if (wv[q] > fv || (wv[q] == fv && wj[q] < fj)) { fv = wv[q]; fj = wj[q]; }
            bjf = fj;
            idx_f[row] = (float)fj;
        }
        __syncthreads();
        if (w == 0 && pm[b * S_FULL + i + 1] == 0) {
            const float4* gp = (const float4*)(Gb + (size_t)bjf * D);
            float4 a0 = gp[lane], a1 = gp[lane + 64], a2 = gp[lane + 128];
            float dx, s = 0.f;
            dx = tr0.x-a0.x; s += dx*dx;  dx = tr0.y-a0.y; s += dx*dx;
            dx = tr0.z-a0.z; s += dx*dx;  dx = tr0.w-a0.w; s += dx*dx;
            dx = tr1.x-a1.x; s += dx*dx;  dx = tr1.y-a1.y; s += dx*dx;
            dx = tr1.z-a1.z; s += dx*dx;  dx = tr1.w-a1.w; s += dx*dx;
            dx = tr2.x-a2.x; s += dx*dx;  dx = tr2.y-a2.y; s += dx*dx;
            dx = tr2.z-a2.z; s += dx*dx;  dx = tr2.w-a2.w; s += dx*dx;
            #pragma unroll
            for (int m = 32; m > 0; m >>= 1) s += __shfl_xor(s, m);
            if (lane == 0) {
                atomicAdd(&acc[64  + (blockIdx.x & 63)], s);
                atomicAdd(&acc[128 + (blockIdx.x & 63)], 1.0f);
            }
        }
        __syncthreads();
    }
}

// ---------------- 5. finalize ----------------
__global__ void finalize_kernel(const float* __restrict__ acc, float* __restrict__ out)
{
    int lane = threadIdx.x;   // 64 threads
    float si = acc[lane], st = acc[64 + lane], sc = acc[128 + lane];
    #pragma unroll
    for (int m = 32; m > 0; m >>= 1) {
        si += __shfl_xor(si, m);
        st += __shfl_xor(st, m);
        sc += __shfl_xor(sc, m);
    }
    if (lane == 0) {
        float img = si / (float)((size_t)B * S_FULL * D);
        float txt = st / (sc * (float)D);
        out[0] = 0.5f * (txt + img);
        out[1] = txt;
        out[2] = img;
    }
}

extern "C" void kernel_launch(void* const* d_in, const int* in_sizes, int n_in,
                              void* d_out, int out_size, void* d_ws, size_t ws_size,
                              hipStream_t stream) {
    const float* image  = (const float*)d_in[0];
    const float* text   = (const float*)d_in[1];
    const float* target = (const float*)d_in[2];
    const int*   pm     = (const int*)d_in[3];
    float* out = (float*)d_out;

    float* ws    = (float*)d_ws;
    float* inv_g = ws + NROWS;                  // NROWS (written by simargmax)
    float* pv    = ws + 2 * NROWS;              // NROWS*4
    float* ps    = ws + 6 * NROWS;              // NROWS*4
    int*   pj    = (int*)(ws + 10 * NROWS);     // NROWS*4
    int*   list  = (int*)(ws + 14 * NROWS);     // NROWS
    int*   cnt   = (int*)(ws + 15 * NROWS);     // 1 (+pad)
    float* acc   = ws + 15 * NROWS + 64;        // 192 slots

    hipMemsetAsync(ws + 15 * NROWS, 0, 256 * sizeof(float), stream);

    prep_kernel<<<B * S_FULL / 4, 256, 0, stream>>>(image, target, acc);
    simargmax_kernel<<<dim3(4, NCHUNK, B), 256, 0, stream>>>(
        text, target, inv_g, pv, ps, pj);
    text_kernel<<<(NROWS + 3) / 4, 256, 0, stream>>>(
        text, target, pm, pv, ps, pj, out + 3, acc, list, cnt);
    recheck_kernel<<<512, 256, 0, stream>>>(
        text, target, pm, inv_g, list, cnt, out + 3, acc);
    finalize_kernel<<<1, 64, 0, stream>>>(acc, out);
}

// Round 6
// 349.466 us; speedup vs baseline: 1.0812x; 1.0812x over previous
//
#include <hip/hip_runtime.h>
#include <math.h>

#define B       32
#define S_FULL  512
#define S       511            // sliced length (drop token 0)
#define D       768
#define NROWS   (B * S)        // 16352

#define TM 128
#define TN 128
#define NCHUNK 4
#define NKT 24                 // D / 32
#define EPS_MARGIN 6e-5f       // fp16-split sim error ~2e-6; margin kept (extra-conservative)
#define SIM_SCALE  512.0f      // lifts fp16 ops out of denormal range; sims scaled by SIM_SCALE^2
#define SIM_SCALE2 (SIM_SCALE * SIM_SCALE)

typedef __attribute__((ext_vector_type(8))) _Float16 f16x8;  // 8 fp16 (4 VGPRs)
typedef __attribute__((ext_vector_type(4))) float f32x4;

// fp16 hi/lo split of 8 consecutive (pre-scaled) floats. HW RNE cvt both ways.
__device__ inline void cvt8(const float4& v0, const float4& v1, float s,
                            f16x8& hv, f16x8& lv) {
    float x[8] = {v0.x, v0.y, v0.z, v0.w, v1.x, v1.y, v1.z, v1.w};
    #pragma unroll
    for (int e = 0; e < 8; ++e) {
        float xs = x[e] * s;
        _Float16 h = (_Float16)xs;          // v_cvt_f16_f32 (RNE)
        hv[e] = h;
        lv[e] = (_Float16)(xs - (float)h);  // residual, |lo| <= 2^-12*|xs|
    }
}

// ---------------- 1. prep: row inv-norms + image loss (shares target read) --
__global__ __launch_bounds__(256) void prep_kernel(
    const float* __restrict__ image, const float* __restrict__ text,
    const float* __restrict__ target,
    float* __restrict__ inv_t, float* __restrict__ inv_g, float* __restrict__ acc)
{
    int row  = blockIdx.x * 4 + (threadIdx.x >> 6);   // 0..B*S_FULL-1
    int lane = threadIdx.x & 63;
    int b = row >> 9, i = row & 511;
    const float4* pi4 = (const float4*)(image  + (size_t)row * D);
    const float4* pt4 = (const float4*)(text   + (size_t)row * D);
    const float4* pg4 = (const float4*)(target + (size_t)row * D);
    float st = 0.f, sg = 0.f, si = 0.f;
    #pragma unroll
    for (int q = 0; q < 3; ++q) {
        float4 a = pt4[lane + 64 * q];
        float4 g = pg4[lane + 64 * q];
        float4 m = pi4[lane + 64 * q];
        st += a.x*a.x + a.y*a.y + a.z*a.z + a.w*a.w;
        sg += g.x*g.x + g.y*g.y + g.z*g.z + g.w*g.w;
        float dx = m.x-g.x, dy = m.y-g.y, dz = m.z-g.z, dw = m.w-g.w;
        si += dx*dx + dy*dy + dz*dz + dw*dw;
    }
    #pragma unroll
    for (int m = 32; m > 0; m >>= 1) {
        st += __shfl_xor(st, m); sg += __shfl_xor(sg, m); si += __shfl_xor(si, m);
    }
    if (lane == 0) {
        atomicAdd(&acc[blockIdx.x & 63], si);
        if (i >= 1) {
            int r = b * S + i - 1;
            inv_t[r] = (st > 0.f) ? 1.f / sqrtf(st) : 0.f;
            inv_g[r] = (sg > 0.f) ? 1.f / sqrtf(sg) : 0.f;
        }
    }
}

// ---------------- 2. split-fp16 MFMA GEMM + per-chunk top-2 ----------------
// grid (4, NCHUNK, B); block 256 (4 waves); block tile 128x128.
// Wave grid 4x1: wave w owns rows [w*32, w*32+32) x ALL 128 cols (one writer/slot).
// LDS: per row 128 B = 8 slots of 16 B: [4 slots hi][4 slots lo], slot ^= (row&7)
// (XOR swizzle on BOTH the 16-B stores and the b128 frag reads -> uniform banks).
__global__ __launch_bounds__(256, 2) void simargmax_kernel(
    const float* __restrict__ text, const float* __restrict__ target,
    const float* __restrict__ inv_t, const float* __restrict__ inv_g,
    float* __restrict__ pv, float* __restrict__ ps, int* __restrict__ pj)
{
    __shared__ __align__(16) _Float16 As[TM * 64];   // 16 KB
    __shared__ __align__(16) _Float16 Bs[TM * 64];   // 16 KB

    const int i0 = blockIdx.x * TM;
    const int jc = blockIdx.y;
    const int j0 = jc * TN;
    const int b  = blockIdx.z;
    const int t  = threadIdx.x;
    const int lane = t & 63;
    const int wy = t >> 6;                    // wave row-strip 0..3
    const int quad = lane >> 4, cid = lane & 15;

    const float* Abase = text   + (size_t)b * S_FULL * D + D;   // skip token 0
    const float* Bbase = target + (size_t)b * S_FULL * D + D;

    // staging map: thread covers 32 contiguous B (8 floats) of one row;
    // 4 threads = 128 B contiguous per row; 2 row-passes (h) cover 128 rows.
    const int r0 = t >> 2;          // 0..63
    const int c0 = t & 3;           // 16-B slot index within hi region
    const int kq = c0 * 8;          // float col offset within the 32-wide k-tile

    float sa[2], sb[2];
    #pragma unroll
    for (int h = 0; h < 2; ++h) {
        int gi = i0 + r0 + 64 * h;
        sa[h] = (gi < S) ? inv_t[b * S + gi] * SIM_SCALE : 0.f;
        int gj = j0 + r0 + 64 * h;
        sb[h] = (gj < S) ? inv_g[b * S + gj] * SIM_SCALE : 0.f;
    }

    const int sw8 = (r0 & 7) * 8;            // store-side swizzle (halfwords)
    const int fw8 = (cid & 7) * 8;           // frag-read swizzle (row&7 == cid&7)
    const int qh  = quad * 8;

    f32x4 acc[2][8];
    #pragma unroll
    for (int mt = 0; mt < 2; ++mt)
        #pragma unroll
        for (int nt = 0; nt < 8; ++nt)
            acc[mt][nt] = (f32x4){0.f, 0.f, 0.f, 0.f};

    for (int kt = 0; kt < NKT; ++kt) {
        const int k0 = kt * 32;
        float4 va[2][2], vb[2][2];
        #pragma unroll
        for (int h = 0; h < 2; ++h) {
            int gi = i0 + r0 + 64 * h;
            if (gi < S) {
                const float4* pa = (const float4*)(Abase + (size_t)gi * D + k0 + kq);
                va[h][0] = pa[0]; va[h][1] = pa[1];
            } else {
                va[h][0] = make_float4(0.f,0.f,0.f,0.f);
                va[h][1] = make_float4(0.f,0.f,0.f,0.f);
            }
            int gj = j0 + r0 + 64 * h;
            if (gj < S) {
                const float4* pb = (const float4*)(Bbase + (size_t)gj * D + k0 + kq);
                vb[h][0] = pb[0]; vb[h][1] = pb[1];
            } else {
                vb[h][0] = make_float4(0.f,0.f,0.f,0.f);
                vb[h][1] = make_float4(0.f,0.f,0.f,0.f);
            }
        }
        __syncthreads();   // prior tile's ds_reads drained before overwrite
        #pragma unroll
        for (int h = 0; h < 2; ++h) {
            int base = (r0 + 64 * h) * 64;
            f16x8 hv, lv;
            cvt8(va[h][0], va[h][1], sa[h], hv, lv);
            *(f16x8*)&As[base + ((c0 * 8)      ^ sw8)] = hv;
            *(f16x8*)&As[base + ((32 + c0 * 8) ^ sw8)] = lv;
            cvt8(vb[h][0], vb[h][1], sb[h], hv, lv);
            *(f16x8*)&Bs[base + ((c0 * 8)      ^ sw8)] = hv;
            *(f16x8*)&Bs[base + ((32 + c0 * 8) ^ sw8)] = lv;
        }
        __syncthreads();

        f16x8 ah[2], al[2];
        #pragma unroll
        for (int mt = 0; mt < 2; ++mt) {
            int ad = (wy * 32 + mt * 16 + cid) * 64;
            ah[mt] = *(const f16x8*)&As[ad + ( qh       ^ fw8)];
            al[mt] = *(const f16x8*)&As[ad + ((32 + qh) ^ fw8)];
        }
        #pragma unroll
        for (int nt = 0; nt < 8; ++nt) {
            int bd = (nt * 16 + cid) * 64;
            f16x8 bh = *(const f16x8*)&Bs[bd + ( qh       ^ fw8)];
            f16x8 bl = *(const f16x8*)&Bs[bd + ((32 + qh) ^ fw8)];
            #pragma unroll
            for (int mt = 0; mt < 2; ++mt) {
                acc[mt][nt] = __builtin_amdgcn_mfma_f32_16x16x32_f16(ah[mt], bh, acc[mt][nt], 0, 0, 0);
                acc[mt][nt] = __builtin_amdgcn_mfma_f32_16x16x32_f16(ah[mt], bl, acc[mt][nt], 0, 0, 0);
                acc[mt][nt] = __builtin_amdgcn_mfma_f32_16x16x32_f16(al[mt], bh, acc[mt][nt], 0, 0, 0);
            }
        }
    }

    // epilogue: per-row top-2 over this chunk's 128 cols (values scaled x2^18).
    // C/D layout: col = cid (within n-tile), row = quad*4 + reg (within m-tile)
    #pragma unroll
    for (int mt = 0; mt < 2; ++mt) {
        #pragma unroll
        for (int r = 0; r < 4; ++r) {
            float v1 = -INFINITY, v2 = -INFINITY; int j1 = -1;
            #pragma unroll
            for (int nt = 0; nt < 8; ++nt) {
                int col = j0 + nt * 16 + cid;
                float v = acc[mt][nt][r];
                if (col < S) {
                    if (v > v1) { v2 = v1; v1 = v; j1 = col; }
                    else if (v > v2) v2 = v;
                }
            }
            #pragma unroll
            for (int m = 1; m < 16; m <<= 1) {
                float ov1 = __shfl_xor(v1, m);
                int   oj1 = __shfl_xor(j1, m);
                float ov2 = __shfl_xor(v2, m);
                if (ov1 > v1) { v2 = fmaxf(v1, ov2); v1 = ov1; j1 = oj1; }
                else          { v2 = fmaxf(v2, ov1); }
            }
            if (cid == 0) {
                int gi = i0 + wy * 32 + mt * 16 + quad * 4 + r;
                if (gi < S) {
                    size_t o = ((size_t)(b * S + gi) << 2) + jc;
                    pv[o] = v1; ps[o] = v2; pj[o] = j1;
                }
            }
        }
    }
}

// ---------------- 3. combine chunks; commit or flag; text loss ----------------
__global__ __launch_bounds__(256) void text_kernel(
    const float* __restrict__ text, const float* __restrict__ target,
    const int* __restrict__ pm,
    const float* __restrict__ pv, const float* __restrict__ ps, const int* __restrict__ pj,
    float* __restrict__ idx_f, float* __restrict__ acc,
    int* __restrict__ list, int* __restrict__ cnt)
{
    int row = blockIdx.x * 4 + (threadIdx.x >> 6);
    if (row >= NROWS) return;
    int lane = threadIdx.x & 63;
    int b = row / S, i = row - b * S;

    float v1 = -INFINITY, v2 = -INFINITY; int j1 = 0;
    #pragma unroll
    for (int c = 0; c < NCHUNK; ++c) {
        size_t o = ((size_t)row << 2) + c;
        float a1 = pv[o], a2 = ps[o]; int aj = pj[o];
        if (a1 > v1) { v2 = fmaxf(v1, a2); v1 = a1; j1 = aj; }
        else         { v2 = fmaxf(v2, a1); }
    }
    if (v1 - v2 < EPS_MARGIN * SIM_SCALE2) {   // too close for split-fp16: exact recheck
        if (lane == 0) { int p = atomicAdd(cnt, 1); list[p] = row; }
        return;
    }
    if (lane == 0) idx_f[row] = (float)j1;

    if (pm[b * S_FULL + i + 1] != 0) return;
    const float4* pt = (const float4*)(text   + (size_t)(b * S_FULL + i  + 1) * D);
    const float4* pg = (const float4*)(target + (size_t)(b * S_FULL + j1 + 1) * D);
    float s = 0.f;
    #pragma unroll
    for (int q = 0; q < 3; ++q) {
        float4 a = pt[lane + 64 * q];
        float4 g = pg[lane + 64 * q];
        float dx = a.x-g.x, dy = a.y-g.y, dz = a.z-g.z, dw = a.w-g.w;
        s += dx*dx + dy*dy + dz*dz + dw*dw;
    }
    #pragma unroll
    for (int m = 32; m > 0; m >>= 1) s += __shfl_xor(s, m);
    if (lane == 0) {
        atomicAdd(&acc[64  + (blockIdx.x & 63)], s);
        atomicAdd(&acc[128 + (blockIdx.x & 63)], 1.0f);
    }
}

// ---------------- 4. exact fp32 argmax re-check (throughput-shaped) ----------
__global__ __launch_bounds__(256) void recheck_kernel(
    const float* __restrict__ text, const float* __restrict__ target,
    const int* __restrict__ pm, const float* __restrict__ inv_g,
    const int* __restrict__ list, const int* __restrict__ cnt,
    float* __restrict__ idx_f, float* __restrict__ acc)
{
    __shared__ float wv[4];
    __shared__ int   wj[4];
    __shared__ int   bjf;
    const int t = threadIdx.x, w = t >> 6, lane = t & 63;
    const int n = *cnt;
    for (int it = blockIdx.x; it < n; it += gridDim.x) {
        int row = list[it];
        int b = row / S, i = row - b * S;
        const float4* tp = (const float4*)(text + (size_t)(b * S_FULL + i + 1) * D);
        float4 tr0 = tp[lane], tr1 = tp[lane + 64], tr2 = tp[lane + 128];
        const float* Gb = target + (size_t)b * S_FULL * D + D;
        const float* ig = inv_g + b * S;

        float bv = -INFINITY; int bj = 0;
        for (int j = w; j < S; j += 8) {       // wave w: j ≡ w (mod 4), 2 per iter
            const float4* g0 = (const float4*)(Gb + (size_t)j * D);
            int j2 = j + 4; bool ok2 = (j2 < S);
            const float4* g1 = (const float4*)(Gb + (size_t)(ok2 ? j2 : j) * D);
            float4 a0 = g0[lane], a1 = g0[lane + 64], a2 = g0[lane + 128];
            float4 c0 = g1[lane], c1 = g1[lane + 64], c2 = g1[lane + 128];
            float s0 = tr0.x*a0.x + tr0.y*a0.y + tr0.z*a0.z + tr0.w*a0.w
                     + tr1.x*a1.x + tr1.y*a1.y + tr1.z*a1.z + tr1.w*a1.w
                     + tr2.x*a2.x + tr2.y*a2.y + tr2.z*a2.z + tr2.w*a2.w;
            float s1 = tr0.x*c0.x + tr0.y*c0.y + tr0.z*c0.z + tr0.w*c0.w
                     + tr1.x*c1.x + tr1.y*c1.y + tr1.z*c1.z + tr1.w*c1.w
                     + tr2.x*c2.x + tr2.y*c2.y + tr2.z*c2.z + tr2.w*c2.w;
            #pragma unroll
            for (int m = 32; m > 0; m >>= 1) {
                s0 += __shfl_xor(s0, m);
                s1 += __shfl_xor(s1, m);
            }
            s0 *= ig[j];
            if (s0 > bv) { bv = s0; bj = j; }       // ascending j: first-max kept
            if (ok2) {
                s1 *= ig[j2];
                if (s1 > bv) { bv = s1; bj = j2; }
            }
        }
        if (lane == 0) { wv[w] = bv; wj[w] = bj; }
        __syncthreads();
        if (t == 0) {
            float fv = wv[0]; int fj = wj[0];
            #pragma unroll
            for (int q = 1; q < 4; ++q)
                if (wv[q] > fv || (wv[q] == fv && wj[q] < fj)) { fv = wv[q]; fj = wj[q]; }
            bjf = fj;
            idx_f[row] = (float)fj;
        }
        __syncthreads();
        if (w == 0 && pm[b * S_FULL + i + 1] == 0) {
            const float4* gp = (const float4*)(Gb + (size_t)bjf * D);
            float4 a0 = gp[lane], a1 = gp[lane + 64], a2 = gp[lane + 128];
            float dx, s = 0.f;
            dx = tr0.x-a0.x; s += dx*dx;  dx = tr0.y-a0.y; s += dx*dx;
            dx = tr0.z-a0.z; s += dx*dx;  dx = tr0.w-a0.w; s += dx*dx;
            dx = tr1.x-a1.x; s += dx*dx;  dx = tr1.y-a1.y; s += dx*dx;
            dx = tr1.z-a1.z; s += dx*dx;  dx = tr1.w-a1.w; s += dx*dx;
            dx = tr2.x-a2.x; s += dx*dx;  dx = tr2.y-a2.y; s += dx*dx;
            dx = tr2.z-a2.z; s += dx*dx;  dx = tr2.w-a2.w; s += dx*dx;
            #pragma unroll
            for (int m = 32; m > 0; m >>= 1) s += __shfl_xor(s, m);
            if (lane == 0) {
                atomicAdd(&acc[64  + (blockIdx.x & 63)], s);
                atomicAdd(&acc[128 + (blockIdx.x & 63)], 1.0f);
            }
        }
        __syncthreads();
    }
}

// ---------------- 5. finalize ----------------
__global__ void finalize_kernel(const float* __restrict__ acc, float* __restrict__ out)
{
    int lane = threadIdx.x;   // 64 threads
    float si = acc[lane], st = acc[64 + lane], sc = acc[128 + lane];
    #pragma unroll
    for (int m = 32; m > 0; m >>= 1) {
        si += __shfl_xor(si, m);
        st += __shfl_xor(st, m);
        sc += __shfl_xor(sc, m);
    }
    if (lane == 0) {
        float img = si / (float)((size_t)B * S_FULL * D);
        float txt = st / (sc * (float)D);
        out[0] = 0.5f * (txt + img);
        out[1] = txt;
        out[2] = img;
    }
}

extern "C" void kernel_launch(void* const* d_in, const int* in_sizes, int n_in,
                              void* d_out, int out_size, void* d_ws, size_t ws_size,
                              hipStream_t stream) {
    const float* image  = (const float*)d_in[0];
    const float* text   = (const float*)d_in[1];
    const float* target = (const float*)d_in[2];
    const int*   pm     = (const int*)d_in[3];
    float* out = (float*)d_out;

    float* ws    = (float*)d_ws;
    float* inv_t = ws;                          // NROWS
    float* inv_g = ws + NROWS;                  // NROWS
    float* pv    = ws + 2 * NROWS;              // NROWS*4
    float* ps    = ws + 6 * NROWS;              // NROWS*4
    int*   pj    = (int*)(ws + 10 * NROWS);     // NROWS*4
    int*   list  = (int*)(ws + 14 * NROWS);     // NROWS
    int*   cnt   = (int*)(ws + 15 * NROWS);     // 1 (+pad)
    float* acc   = ws + 15 * NROWS + 64;        // 192 slots

    hipMemsetAsync(ws + 15 * NROWS, 0, 256 * sizeof(float), stream);

    prep_kernel<<<B * S_FULL / 4, 256, 0, stream>>>(image, text, target, inv_t, inv_g, acc);
    simargmax_kernel<<<dim3(4, NCHUNK, B), 256, 0, stream>>>(
        text, target, inv_t, inv_g, pv, ps, pj);
    text_kernel<<<(NROWS + 3) / 4, 256, 0, stream>>>(
        text, target, pm, pv, ps, pj, out + 3, acc, list, cnt);
    recheck_kernel<<<512, 256, 0, stream>>>(
        text, target, pm, inv_g, list, cnt, out + 3, acc);
    finalize_kernel<<<1, 64, 0, stream>>>(acc, out);
}

// Round 7
// 304.612 us; speedup vs baseline: 1.2404x; 1.1472x over previous
//
#include <hip/hip_runtime.h>
#include <math.h>

#define B       32
#define S_FULL  512
#define S       511            // sliced length (drop token 0)
#define D       768
#define NROWS   (B * S)        // 16352

#define TM 128
#define TN 128
#define NCHUNK 4
#define NKT 24                 // D / 32
#define EPS_MARGIN 6e-5f       // fp16-split sim error ~2e-6; margin kept (extra-conservative)
#define SIM_SCALE  512.0f      // lifts fp16 ops out of denormal range; sims scaled by SIM_SCALE^2
#define SIM_SCALE2 (SIM_SCALE * SIM_SCALE)

#define NPREP   (B * S_FULL / 4)   // 4096 prep blocks -> per-block partials

typedef __attribute__((ext_vector_type(8))) _Float16 f16x8;  // 8 fp16 (4 VGPRs)
typedef __attribute__((ext_vector_type(4))) float f32x4;

// fp16 hi/lo split of 8 consecutive (pre-scaled) floats. HW RNE cvt both ways.
__device__ inline void cvt8(const float4& v0, const float4& v1, float s,
                            f16x8& hv, f16x8& lv) {
    float x[8] = {v0.x, v0.y, v0.z, v0.w, v1.x, v1.y, v1.z, v1.w};
    #pragma unroll
    for (int e = 0; e < 8; ++e) {
        float xs = x[e] * s;
        _Float16 h = (_Float16)xs;          // v_cvt_f16_f32 (RNE)
        hv[e] = h;
        lv[e] = (_Float16)(xs - (float)h);  // residual, |lo| <= 2^-12*|xs|
    }
}

// ---------------- 1. prep: row inv-norms + image loss (shares target read) --
// G12: per-block LDS reduction, ZERO atomics — partial -> pimg[blockIdx.x].
__global__ __launch_bounds__(256) void prep_kernel(
    const float* __restrict__ image, const float* __restrict__ text,
    const float* __restrict__ target,
    float* __restrict__ inv_t, float* __restrict__ inv_g, float* __restrict__ pimg)
{
    __shared__ float warr[4];
    int w    = threadIdx.x >> 6;
    int row  = blockIdx.x * 4 + w;                    // 0..B*S_FULL-1
    int lane = threadIdx.x & 63;
    int b = row >> 9, i = row & 511;
    const float4* pi4 = (const float4*)(image  + (size_t)row * D);
    const float4* pt4 = (const float4*)(text   + (size_t)row * D);
    const float4* pg4 = (const float4*)(target + (size_t)row * D);
    float st = 0.f, sg = 0.f, si = 0.f;
    #pragma unroll
    for (int q = 0; q < 3; ++q) {
        float4 a = pt4[lane + 64 * q];
        float4 g = pg4[lane + 64 * q];
        float4 m = pi4[lane + 64 * q];
        st += a.x*a.x + a.y*a.y + a.z*a.z + a.w*a.w;
        sg += g.x*g.x + g.y*g.y + g.z*g.z + g.w*g.w;
        float dx = m.x-g.x, dy = m.y-g.y, dz = m.z-g.z, dw = m.w-g.w;
        si += dx*dx + dy*dy + dz*dz + dw*dw;
    }
    #pragma unroll
    for (int m = 32; m > 0; m >>= 1) {
        st += __shfl_xor(st, m); sg += __shfl_xor(sg, m); si += __shfl_xor(si, m);
    }
    if (lane == 0) {
        warr[w] = si;
        if (i >= 1) {
            int r = b * S + i - 1;
            inv_t[r] = (st > 0.f) ? 1.f / sqrtf(st) : 0.f;
            inv_g[r] = (sg > 0.f) ? 1.f / sqrtf(sg) : 0.f;
        }
    }
    __syncthreads();
    if (threadIdx.x == 0)
        pimg[blockIdx.x] = warr[0] + warr[1] + warr[2] + warr[3];
}

// ---------------- 2. split-fp16 MFMA GEMM + per-chunk top-2 ----------------
// grid (4, NCHUNK, B); block 256 (4 waves); block tile 128x128.
// Wave grid 4x1: wave w owns rows [w*32, w*32+32) x ALL 128 cols (one writer/slot).
// LDS: per row 128 B = 8 slots of 16 B: [4 slots hi][4 slots lo], slot ^= (row&7)
// (XOR swizzle on BOTH the 16-B stores and the b128 frag reads -> uniform banks).
__global__ __launch_bounds__(256, 2) void simargmax_kernel(
    const float* __restrict__ text, const float* __restrict__ target,
    const float* __restrict__ inv_t, const float* __restrict__ inv_g,
    float* __restrict__ pv, float* __restrict__ ps, int* __restrict__ pj)
{
    __shared__ __align__(16) _Float16 As[TM * 64];   // 16 KB
    __shared__ __align__(16) _Float16 Bs[TM * 64];   // 16 KB

    const int i0 = blockIdx.x * TM;
    const int jc = blockIdx.y;
    const int j0 = jc * TN;
    const int b  = blockIdx.z;
    const int t  = threadIdx.x;
    const int lane = t & 63;
    const int wy = t >> 6;                    // wave row-strip 0..3
    const int quad = lane >> 4, cid = lane & 15;

    const float* Abase = text   + (size_t)b * S_FULL * D + D;   // skip token 0
    const float* Bbase = target + (size_t)b * S_FULL * D + D;

    // staging map: thread covers 32 contiguous B (8 floats) of one row;
    // 4 threads = 128 B contiguous per row; 2 row-passes (h) cover 128 rows.
    const int r0 = t >> 2;          // 0..63
    const int c0 = t & 3;           // 16-B slot index within hi region
    const int kq = c0 * 8;          // float col offset within the 32-wide k-tile

    float sa[2], sb[2];
    #pragma unroll
    for (int h = 0; h < 2; ++h) {
        int gi = i0 + r0 + 64 * h;
        sa[h] = (gi < S) ? inv_t[b * S + gi] * SIM_SCALE : 0.f;
        int gj = j0 + r0 + 64 * h;
        sb[h] = (gj < S) ? inv_g[b * S + gj] * SIM_SCALE : 0.f;
    }

    const int sw8 = (r0 & 7) * 8;            // store-side swizzle (halfwords)
    const int fw8 = (cid & 7) * 8;           // frag-read swizzle (row&7 == cid&7)
    const int qh  = quad * 8;

    f32x4 acc[2][8];
    #pragma unroll
    for (int mt = 0; mt < 2; ++mt)
        #pragma unroll
        for (int nt = 0; nt < 8; ++nt)
            acc[mt][nt] = (f32x4){0.f, 0.f, 0.f, 0.f};

    for (int kt = 0; kt < NKT; ++kt) {
        const int k0 = kt * 32;
        float4 va[2][2], vb[2][2];
        #pragma unroll
        for (int h = 0; h < 2; ++h) {
            int gi = i0 + r0 + 64 * h;
            if (gi < S) {
                const float4* pa = (const float4*)(Abase + (size_t)gi * D + k0 + kq);
                va[h][0] = pa[0]; va[h][1] = pa[1];
            } else {
                va[h][0] = make_float4(0.f,0.f,0.f,0.f);
                va[h][1] = make_float4(0.f,0.f,0.f,0.f);
            }
            int gj = j0 + r0 + 64 * h;
            if (gj < S) {
                const float4* pb = (const float4*)(Bbase + (size_t)gj * D + k0 + kq);
                vb[h][0] = pb[0]; vb[h][1] = pb[1];
            } else {
                vb[h][0] = make_float4(0.f,0.f,0.f,0.f);
                vb[h][1] = make_float4(0.f,0.f,0.f,0.f);
            }
        }
        __syncthreads();   // prior tile's ds_reads drained before overwrite
        #pragma unroll
        for (int h = 0; h < 2; ++h) {
            int base = (r0 + 64 * h) * 64;
            f16x8 hv, lv;
            cvt8(va[h][0], va[h][1], sa[h], hv, lv);
            *(f16x8*)&As[base + ((c0 * 8)      ^ sw8)] = hv;
            *(f16x8*)&As[base + ((32 + c0 * 8) ^ sw8)] = lv;
            cvt8(vb[h][0], vb[h][1], sb[h], hv, lv);
            *(f16x8*)&Bs[base + ((c0 * 8)      ^ sw8)] = hv;
            *(f16x8*)&Bs[base + ((32 + c0 * 8) ^ sw8)] = lv;
        }
        __syncthreads();

        f16x8 ah[2], al[2];
        #pragma unroll
        for (int mt = 0; mt < 2; ++mt) {
            int ad = (wy * 32 + mt * 16 + cid) * 64;
            ah[mt] = *(const f16x8*)&As[ad + ( qh       ^ fw8)];
            al[mt] = *(const f16x8*)&As[ad + ((32 + qh) ^ fw8)];
        }
        #pragma unroll
        for (int nt = 0; nt < 8; ++nt) {
            int bd = (nt * 16 + cid) * 64;
            f16x8 bh = *(const f16x8*)&Bs[bd + ( qh       ^ fw8)];
            f16x8 bl = *(const f16x8*)&Bs[bd + ((32 + qh) ^ fw8)];
            #pragma unroll
            for (int mt = 0; mt < 2; ++mt) {
                acc[mt][nt] = __builtin_amdgcn_mfma_f32_16x16x32_f16(ah[mt], bh, acc[mt][nt], 0, 0, 0);
                acc[mt][nt] = __builtin_amdgcn_mfma_f32_16x16x32_f16(ah[mt], bl, acc[mt][nt], 0, 0, 0);
                acc[mt][nt] = __builtin_amdgcn_mfma_f32_16x16x32_f16(al[mt], bh, acc[mt][nt], 0, 0, 0);
            }
        }
    }

    // epilogue: per-row top-2 over this chunk's 128 cols (values scaled x2^18).
    // C/D layout: col = cid (within n-tile), row = quad*4 + reg (within m-tile)
    #pragma unroll
    for (int mt = 0; mt < 2; ++mt) {
        #pragma unroll
        for (int r = 0; r < 4; ++r) {
            float v1 = -INFINITY, v2 = -INFINITY; int j1 = -1;
            #pragma unroll
            for (int nt = 0; nt < 8; ++nt) {
                int col = j0 + nt * 16 + cid;
                float v = acc[mt][nt][r];
                if (col < S) {
                    if (v > v1) { v2 = v1; v1 = v; j1 = col; }
                    else if (v > v2) v2 = v;
                }
            }
            #pragma unroll
            for (int m = 1; m < 16; m <<= 1) {
                float ov1 = __shfl_xor(v1, m);
                int   oj1 = __shfl_xor(j1, m);
                float ov2 = __shfl_xor(v2, m);
                if (ov1 > v1) { v2 = fmaxf(v1, ov2); v1 = ov1; j1 = oj1; }
                else          { v2 = fmaxf(v2, ov1); }
            }
            if (cid == 0) {
                int gi = i0 + wy * 32 + mt * 16 + quad * 4 + r;
                if (gi < S) {
                    size_t o = ((size_t)(b * S + gi) << 2) + jc;
                    pv[o] = v1; ps[o] = v2; pj[o] = j1;
                }
            }
        }
    }
}

// ---------------- 3. combine chunks; commit or flag; text loss ----------------
// G12: block-level LDS reduce of (s, count); ONE atomicAdd pair per block.
__global__ __launch_bounds__(256) void text_kernel(
    const float* __restrict__ text, const float* __restrict__ target,
    const int* __restrict__ pm,
    const float* __restrict__ pv, const float* __restrict__ ps, const int* __restrict__ pj,
    float* __restrict__ idx_f, float* __restrict__ acc,
    int* __restrict__ list, int* __restrict__ cnt)
{
    __shared__ float ls[4], lc[4];
    int w   = threadIdx.x >> 6;
    int row = blockIdx.x * 4 + w;      // grid covers rows exactly (4*4088=16352)
    int lane = threadIdx.x & 63;
    int b = row / S, i = row - b * S;

    float v1 = -INFINITY, v2 = -INFINITY; int j1 = 0;
    #pragma unroll
    for (int c = 0; c < NCHUNK; ++c) {
        size_t o = ((size_t)row << 2) + c;
        float a1 = pv[o], a2 = ps[o]; int aj = pj[o];
        if (a1 > v1) { v2 = fmaxf(v1, a2); v1 = a1; j1 = aj; }
        else         { v2 = fmaxf(v2, a1); }
    }

    float s = 0.f, c1 = 0.f;
    if (v1 - v2 < EPS_MARGIN * SIM_SCALE2) {   // too close for split-fp16: exact recheck
        if (lane == 0) { int p = atomicAdd(cnt, 1); list[p] = row; }
    } else {
        if (lane == 0) idx_f[row] = (float)j1;
        if (pm[b * S_FULL + i + 1] == 0) {
            const float4* pt = (const float4*)(text   + (size_t)(b * S_FULL + i  + 1) * D);
            const float4* pg = (const float4*)(target + (size_t)(b * S_FULL + j1 + 1) * D);
            #pragma unroll
            for (int q = 0; q < 3; ++q) {
                float4 a = pt[lane + 64 * q];
                float4 g = pg[lane + 64 * q];
                float dx = a.x-g.x, dy = a.y-g.y, dz = a.z-g.z, dw = a.w-g.w;
                s += dx*dx + dy*dy + dz*dz + dw*dw;
            }
            #pragma unroll
            for (int m = 32; m > 0; m >>= 1) s += __shfl_xor(s, m);
            c1 = 1.f;
        }
    }
    if (lane == 0) { ls[w] = s; lc[w] = c1; }
    __syncthreads();
    if (threadIdx.x == 0) {
        float S4 = ls[0] + ls[1] + ls[2] + ls[3];
        float C4 = lc[0] + lc[1] + lc[2] + lc[3];
        if (C4 > 0.f) {
            atomicAdd(&acc[64  + (blockIdx.x & 63)], S4);
            atomicAdd(&acc[128 + (blockIdx.x & 63)], C4);
        }
    }
}

// ---------------- 4. exact fp32 argmax re-check (throughput-shaped) ----------
__global__ __launch_bounds__(256) void recheck_kernel(
    const float* __restrict__ text, const float* __restrict__ target,
    const int* __restrict__ pm, const float* __restrict__ inv_g,
    const int* __restrict__ list, const int* __restrict__ cnt,
    float* __restrict__ idx_f, float* __restrict__ acc)
{
    __shared__ float wv[4];
    __shared__ int   wj[4];
    __shared__ int   bjf;
    const int t = threadIdx.x, w = t >> 6, lane = t & 63;
    const int n = *cnt;
    for (int it = blockIdx.x; it < n; it += gridDim.x) {
        int row = list[it];
        int b = row / S, i = row - b * S;
        const float4* tp = (const float4*)(text + (size_t)(b * S_FULL + i + 1) * D);
        float4 tr0 = tp[lane], tr1 = tp[lane + 64], tr2 = tp[lane + 128];
        const float* Gb = target + (size_t)b * S_FULL * D + D;
        const float* ig = inv_g + b * S;

        float bv = -INFINITY; int bj = 0;
        for (int j = w; j < S; j += 8) {       // wave w: j ≡ w (mod 4), 2 per iter
            const float4* g0 = (const float4*)(Gb + (size_t)j * D);
            int j2 = j + 4; bool ok2 = (j2 < S);
            const float4* g1 = (const float4*)(Gb + (size_t)(ok2 ? j2 : j) * D);
            float4 a0 = g0[lane], a1 = g0[lane + 64], a2 = g0[lane + 128];
            float4 c0 = g1[lane], c1 = g1[lane + 64], c2 = g1[lane + 128];
            float s0 = tr0.x*a0.x + tr0.y*a0.y + tr0.z*a0.z + tr0.w*a0.w
                     + tr1.x*a1.x + tr1.y*a1.y + tr1.z*a1.z + tr1.w*a1.w
                     + tr2.x*a2.x + tr2.y*a2.y + tr2.z*a2.z + tr2.w*a2.w;
            float s1 = tr0.x*c0.x + tr0.y*c0.y + tr0.z*c0.z + tr0.w*c0.w
                     + tr1.x*c1.x + tr1.y*c1.y + tr1.z*c1.z + tr1.w*c1.w
                     + tr2.x*c2.x + tr2.y*c2.y + tr2.z*c2.z + tr2.w*c2.w;
            #pragma unroll
            for (int m = 32; m > 0; m >>= 1) {
                s0 += __shfl_xor(s0, m);
                s1 += __shfl_xor(s1, m);
            }
            s0 *= ig[j];
            if (s0 > bv) { bv = s0; bj = j; }       // ascending j: first-max kept
            if (ok2) {
                s1 *= ig[j2];
                if (s1 > bv) { bv = s1; bj = j2; }
            }
        }
        if (lane == 0) { wv[w] = bv; wj[w] = bj; }
        __syncthreads();
        if (t == 0) {
            float fv = wv[0]; int fj = wj[0];
            #pragma unroll
            for (int q = 1; q < 4; ++q)
                if (wv[q] > fv || (wv[q] == fv && wj[q] < fj)) { fv = wv[q]; fj = wj[q]; }
            bjf = fj;
            idx_f[row] = (float)fj;
        }
        __syncthreads();
        if (w == 0 && pm[b * S_FULL + i + 1] == 0) {
            const float4* gp = (const float4*)(Gb + (size_t)bjf * D);
            float4 a0 = gp[lane], a1 = gp[lane + 64], a2 = gp[lane + 128];
            float dx, s = 0.f;
            dx = tr0.x-a0.x; s += dx*dx;  dx = tr0.y-a0.y; s += dx*dx;
            dx = tr0.z-a0.z; s += dx*dx;  dx = tr0.w-a0.w; s += dx*dx;
            dx = tr1.x-a1.x; s += dx*dx;  dx = tr1.y-a1.y; s += dx*dx;
            dx = tr1.z-a1.z; s += dx*dx;  dx = tr1.w-a1.w; s += dx*dx;
            dx = tr2.x-a2.x; s += dx*dx;  dx = tr2.y-a2.y; s += dx*dx;
            dx = tr2.z-a2.z; s += dx*dx;  dx = tr2.w-a2.w; s += dx*dx;
            #pragma unroll
            for (int m = 32; m > 0; m >>= 1) s += __shfl_xor(s, m);
            if (lane == 0) {
                atomicAdd(&acc[64  + (blockIdx.x & 63)], s);
                atomicAdd(&acc[128 + (blockIdx.x & 63)], 1.0f);
            }
        }
        __syncthreads();
    }
}

// ---------------- 5. finalize: sum 4096 prep partials + acc slots ----------
__global__ __launch_bounds__(256) void finalize_kernel(
    const float* __restrict__ acc, const float* __restrict__ pimg,
    float* __restrict__ out)
{
    __shared__ float r[12];
    int t = threadIdx.x, lane = t & 63, w = t >> 6;
    float si = 0.f;
    for (int i = t; i < NPREP; i += 256) si += pimg[i];
    float st = (t < 64) ? acc[64 + t]  : 0.f;
    float sc = (t < 64) ? acc[128 + t] : 0.f;
    #pragma unroll
    for (int m = 32; m > 0; m >>= 1) {
        si += __shfl_xor(si, m);
        st += __shfl_xor(st, m);
        sc += __shfl_xor(sc, m);
    }
    if (lane == 0) { r[w] = si; r[4 + w] = st; r[8 + w] = sc; }
    __syncthreads();
    if (t == 0) {
        si = r[0] + r[1] + r[2] + r[3];
        st = r[4] + r[5] + r[6] + r[7];
        sc = r[8] + r[9] + r[10] + r[11];
        float img = si / (float)((size_t)B * S_FULL * D);
        float txt = st / (sc * (float)D);
        out[0] = 0.5f * (txt + img);
        out[1] = txt;
        out[2] = img;
    }
}

extern "C" void kernel_launch(void* const* d_in, const int* in_sizes, int n_in,
                              void* d_out, int out_size, void* d_ws, size_t ws_size,
                              hipStream_t stream) {
    const float* image  = (const float*)d_in[0];
    const float* text   = (const float*)d_in[1];
    const float* target = (const float*)d_in[2];
    const int*   pm     = (const int*)d_in[3];
    float* out = (float*)d_out;

    float* ws    = (float*)d_ws;
    float* inv_t = ws;                          // NROWS
    float* inv_g = ws + NROWS;                  // NROWS
    float* pv    = ws + 2 * NROWS;              // NROWS*4
    float* ps    = ws + 6 * NROWS;              // NROWS*4
    int*   pj    = (int*)(ws + 10 * NROWS);     // NROWS*4
    int*   list  = (int*)(ws + 14 * NROWS);     // NROWS
    int*   cnt   = (int*)(ws + 15 * NROWS);     // 1 (+pad)
    float* acc   = ws + 15 * NROWS + 64;        // 192 slots
    float* pimg  = ws + 15 * NROWS + 256;       // NPREP per-block partials

    hipMemsetAsync(ws + 15 * NROWS, 0, 256 * sizeof(float), stream);

    prep_kernel<<<NPREP, 256, 0, stream>>>(image, text, target, inv_t, inv_g, pimg);
    simargmax_kernel<<<dim3(4, NCHUNK, B), 256, 0, stream>>>(
        text, target, inv_t, inv_g, pv, ps, pj);
    text_kernel<<<(NROWS + 3) / 4, 256, 0, stream>>>(
        text, target, pm, pv, ps, pj, out + 3, acc, list, cnt);
    recheck_kernel<<<512, 256, 0, stream>>>(
        text, target, pm, inv_g, list, cnt, out + 3, acc);
    finalize_kernel<<<1, 256, 0, stream>>>(acc, pimg, out);
}